// Round 16
// baseline (131.844 us; speedup 1.0000x reference)
//
#include <hip/hip_runtime.h>
#include <hip/hip_bf16.h>

typedef unsigned int uint;
typedef unsigned short ushort;
typedef unsigned long long ull;
typedef __attribute__((ext_vector_type(8))) short short8;
typedef __attribute__((ext_vector_type(4))) float float4_;

#define B_TOT 32768
#define NL    22
#define HID0  ((long)B_TOT * 20)

// ws layout (bytes), 16B aligned
#define W2F_OFF  0          // conv2 B-frags bf16 (k = ic*9+p): 294,912
#define WFCF_OFF 294912     // fc    B-frags bf16: 65,536
#define WHF_OFF  360448     // heads B-frags bf16: 32,768
#define W1P_OFF  393216     // conv1 W^T bf16-pairs: 551*64*4 = 141,056
#define H1_OFF   534272     // h1 row-major bf16: 32768*1152*2 = 75,497,472
// total 76,031,744

__device__ __forceinline__ ushort f2bf(float v) {
  uint x = __float_as_uint(v);
  x += 0x7fffu + ((x >> 16) & 1u);
  return (ushort)(x >> 16);
}
__device__ __forceinline__ uint cvtpk(float lo, float hi) {
  uint r;
  asm volatile("v_cvt_pk_bf16_f32 %0, %1, %2" : "=v"(r) : "v"(lo), "v"(hi));
  return r;
}
struct u3 { uint x, y, z; };

// ---------------- prologue: weight repack ----------------
extern "C" __global__ __launch_bounds__(256)
void k_prep(const float* __restrict__ wc1, const float* __restrict__ wc2,
            const float* __restrict__ wfc,
            const float* __restrict__ wa0, const float* __restrict__ wa1,
            const float* __restrict__ wv,
            ushort* __restrict__ w2f, ushort* __restrict__ wfcf,
            ushort* __restrict__ whf, uint* __restrict__ w1p)
{
  int i = blockIdx.x * 256 + threadIdx.x;
  if (i < 18432) {            // conv2 B-frags: B[k][col] = wc2[col][k], k = ic*9+p
    int l = i & 63, cg = (i >> 6) & 7, ks = i >> 9;
    int col = cg * 16 + (l & 15), kb = ks * 32 + (l >> 4) * 8;
    ushort t[8];
    #pragma unroll
    for (int j = 0; j < 8; ++j) t[j] = f2bf(wc2[col * 1152 + kb + j]);
    uint4 o = { (uint)t[0]|((uint)t[1]<<16), (uint)t[2]|((uint)t[3]<<16),
                (uint)t[4]|((uint)t[5]<<16), (uint)t[6]|((uint)t[7]<<16) };
    ((uint4*)w2f)[i] = o;
  } else if (i < 22528) {     // fc: B[k][col] = wfc[k][col]
    int i2 = i - 18432;
    int l = i2 & 63, cg = (i2 >> 6) & 15, ks = i2 >> 10;
    int col = cg * 16 + (l & 15), kb = ks * 32 + (l >> 4) * 8;
    ushort t[8];
    #pragma unroll
    for (int j = 0; j < 8; ++j) t[j] = f2bf(wfc[(kb + j) * 256 + col]);
    uint4 o = { (uint)t[0]|((uint)t[1]<<16), (uint)t[2]|((uint)t[3]<<16),
                (uint)t[4]|((uint)t[5]<<16), (uint)t[6]|((uint)t[7]<<16) };
    ((uint4*)wfcf)[i2] = o;
  } else if (i < 24576) {     // heads: cols 0..8 wa0, 9..18 wa1, 19 wv, 20..31 zero
    int i2 = i - 22528;
    int l = i2 & 63, cg = (i2 >> 6) & 1, ks = i2 >> 7;
    int col = cg * 16 + (l & 15), kb = ks * 32 + (l >> 4) * 8;
    ushort t[8];
    #pragma unroll
    for (int j = 0; j < 8; ++j) {
      int k = kb + j;
      float v = (col < 9)  ? wa0[k*9 + col]
              : (col < 19) ? wa1[k*10 + (col - 9)]
              : (col == 19) ? wv[k] : 0.f;
      t[j] = f2bf(v);
    }
    uint4 o = { (uint)t[0]|((uint)t[1]<<16), (uint)t[2]|((uint)t[3]<<16),
                (uint)t[4]|((uint)t[5]<<16), (uint)t[6]|((uint)t[7]<<16) };
    ((uint4*)whf)[i2] = o;
  } else if (i < 24576 + 35264) {   // w1p: 550 packed rows (+spare zero row)
    int j = i - 24576;
    int l = j & 63, r = j >> 6;
    uint val = 0u;
    if (r < 550) {
      ushort lo_ = f2bf(wc1[(2*l)     * 550 + r]);
      ushort hi_ = f2bf(wc1[(2*l + 1) * 550 + r]);
      val = (uint)lo_ | ((uint)hi_ << 16);
    }
    w1p[j] = val;
  }
}

// ---- scalar decode of one token + issue its <=4 (dup-clamped) loads ----
// stride-3 5x5 on 11-grid: at most 2 ox and 2 oy values per token.
// Decode geometry correctness-proven in round 14 (passed absmax).
#define TB_DECODE(S, tk)                                                   \
  const uint a_##S = (tk) >> 16, x_##S = ((tk) >> 12) & 15u,               \
             y_##S = ((tk) >> 8) & 15u, val_##S = (tk) & 255u;             \
  const float rmv_##S = __int_as_float(                                    \
      __builtin_amdgcn_readlane(__float_as_int(rm_own), a_##S));           \
  const float fv_##S = (float)val_##S * rmv_##S;                           \
  const int oxl_##S = (x_##S >= 5u) ? ((int)x_##S - 2) / 3 : 0;            \
  const int oyl_##S = (y_##S >= 5u) ? ((int)y_##S - 2) / 3 : 0;            \
  const int oxh_##S = ((int)x_##S / 3 > 2) ? 2 : (int)x_##S / 3;           \
  const int oyh_##S = ((int)y_##S / 3 > 2) ? 2 : (int)y_##S / 3;           \
  const bool nx_##S = oxh_##S > oxl_##S, ny_##S = oyh_##S > oyl_##S;       \
  const int w00_##S = (int)a_##S * 25 + ((int)x_##S - 3*oxl_##S) * 5       \
                      + ((int)y_##S - 3*oyl_##S);                          \
  const int w01_##S = ny_##S ? (w00_##S - 3)  : w00_##S;                   \
  const int w10_##S = nx_##S ? (w00_##S - 15) : w00_##S;                   \
  const int w11_##S = (nx_##S && ny_##S) ? (w00_##S - 18) : w00_##S;       \
  const uint u00_##S = w1p[w00_##S * 64 + lane];                           \
  const uint u01_##S = w1p[w01_##S * 64 + lane];                           \
  const uint u10_##S = w1p[w10_##S * 64 + lane];                           \
  const uint u11_##S = w1p[w11_##S * 64 + lane];

// ---- consumer: static-unrolled positions, SCALAR branches gating pure
// register VALU (no loads, no waits). Accumulator indices compile-time. ----
#define TB_FMA(S, acc0, acc1)                                              \
  _Pragma("unroll")                                                        \
  for (int ox = 0; ox < 3; ++ox) {                                         \
    if (ox < oxl_##S || ox > oxh_##S) continue;   /* s_cmp + s_cbranch */  \
    _Pragma("unroll")                                                      \
    for (int oy = 0; oy < 3; ++oy) {                                       \
      if (oy < oyl_##S || oy > oyh_##S) continue;                          \
      uint wu = (ox == oxl_##S) ? ((oy == oyl_##S) ? u00_##S : u01_##S)    \
                                : ((oy == oyl_##S) ? u10_##S : u11_##S);   \
      acc0[ox*3+oy] = fmaf(fv_##S, __uint_as_float(wu << 16),              \
                           acc0[ox*3+oy]);                                 \
      acc1[ox*3+oy] = fmaf(fv_##S, __uint_as_float(wu & 0xffff0000u),      \
                           acc1[ox*3+oy]);                                 \
    }                                                                      \
  }

// extract next token from ballot mask (dummy 0 when exhausted: fv=0, p(0,0))
#define NEXT_TOKEN(m, u, tk)                                               \
  {                                                                        \
    int _i = __builtin_ctzll((m) | 0x8000000000000000ull);                 \
    uint _t = (uint)__builtin_amdgcn_readlane((int)(u), _i);               \
    (tk) = (m) ? _t : 0u;                                                  \
    (m) &= (m) - 1ull;                                                     \
  }

// ---------------- kernel 1: tokens -> sparse conv1 + self head ----------------
// 2 samples/wave; token loop processes 4 tokens/iteration (2 per sample):
// all 16 w1p loads issue branch-free up front (one amortized wait), then
// scalar-branch register-only FMAs (r13 structure, but no load under branch).
extern "C" __global__ __launch_bounds__(256)
void k_encode(const int* __restrict__ obs, const float* __restrict__ maxvec,
              const uint* __restrict__ w1p, const float* __restrict__ bc1,
              const float* __restrict__ wself, const float* __restrict__ bself,
              float* __restrict__ out, ushort* __restrict__ h1g)
{
  __shared__ uint klist[8][64];

  const int tid = threadIdx.x, lane = tid & 63, w = tid >> 6;
  const long bA = (long)blockIdx.x * 8 + w * 2;
  const long bB = bA + 1;

  float rm_own = (lane < NL) ? (1.0f / maxvec[lane]) : 0.f;

  const uint* obA = (const uint*)obs + bA * 600;
  const uint* obB = (const uint*)obs + bB * 600;
  uint* klA = klist[w * 2 + 0];
  uint* klB = klist[w * 2 + 1];

  // ---- decode + ordered compaction, A/B interleaved ----
  int cntA = 0, cntB = 0;
  #pragma unroll
  for (int r = 0; r < 4; ++r) {
    int m = r * 64 + lane;
    bool vA = false, vB = false; uint pkA = 0, pkB = 0;
    if (m < 200) {
      u3 tA = *(const u3*)(obA + m * 3);
      u3 tB = *(const u3*)(obB + m * 3);
      uint cA = tA.x, aA = tA.y, vvA = tA.z;
      uint cB = tB.x, aB = tB.y, vvB = tB.z;
      cA = (cA == 255u) ? 0u : cA;  aA = (aA == 255u) ? 0u : aA;  vvA = (vvA == 255u) ? 0u : vvA;
      cB = (cB == 255u) ? 0u : cB;  aB = (aB == 255u) ? 0u : aB;  vvB = (vvB == 255u) ? 0u : vvB;
      uint xA = (cA >> 4) & 15u, yA = cA & 15u;
      uint xB = (cB >> 4) & 15u, yB = cB & 15u;
      vA = (xA < 11u) && (yA < 11u) && (aA < NL);
      vB = (xB < 11u) && (yB < 11u) && (aB < NL);
      pkA = (aA << 16) | (xA << 12) | (yA << 8) | vvA;
      pkB = (aB << 16) | (xB << 12) | (yB << 8) | vvB;
    }
    ull balA = __ballot(vA);
    if (vA) {
      int pos = cntA + __popcll(balA & ((1ull << lane) - 1ull));
      if (pos < 64) klA[pos] = pkA;
    }
    cntA += __popcll(balA);
    ull balB = __ballot(vB);
    if (vB) {
      int pos = cntB + __popcll(balB & ((1ull << lane) - 1ull));
      if (pos < 64) klB[pos] = pkB;
    }
    cntB += __popcll(balB);
  }
  if (cntA > 64) cntA = 64;
  if (cntB > 64) cntB = 64;

  // ---- dedup (last write wins) in registers, fused shfl ring scan ----
  uint uA = (lane < cntA) ? klA[lane] : 0xffffffffu;
  uint uB = (lane < cntB) ? klB[lane] : 0xffffffffu;
  uint cellA = uA >> 8, cellB = uB >> 8;
  bool aliveA = (lane < cntA), aliveB = (lane < cntB);
  const int dmax = (cntA > cntB) ? cntA : cntB;
  for (int d = 1; d < dmax; ++d) {
    uint oA = __shfl_down(cellA, d);
    uint oB = __shfl_down(cellB, d);
    aliveA = aliveA && !((lane + d < cntA) && (oA == cellA));
    aliveB = aliveB && !((lane + d < cntB) && (oB == cellB));
  }
  const ull balA2 = __ballot(aliveA);
  const ull balB2 = __ballot(aliveB);

  // ---- self head: rare (5,5) tokens, uniform scalar pre-pass ----
  float2 saA = {0.f,0.f}, sbA = {0.f,0.f}, saB = {0.f,0.f}, sbB = {0.f,0.f};
  {
    ull b55 = __ballot(aliveA && (((uA >> 12) & 15u) == 5u) && (((uA >> 8) & 15u) == 5u));
    while (b55) {
      int idx = __builtin_ctzll(b55); b55 &= b55 - 1ull;
      uint tk = (uint)__builtin_amdgcn_readlane((int)uA, idx);
      int a = tk >> 16;
      float rmv = __int_as_float(__builtin_amdgcn_readlane(__float_as_int(rm_own), a));
      float fv = (float)(tk & 255u) * rmv;
      const float2* ws2 = (const float2*)(wself + a * 256);
      float2 w0 = ws2[lane], w1 = ws2[64 + lane];
      saA.x = fmaf(fv, w0.x, saA.x);  saA.y = fmaf(fv, w0.y, saA.y);
      sbA.x = fmaf(fv, w1.x, sbA.x);  sbA.y = fmaf(fv, w1.y, sbA.y);
    }
    b55 = __ballot(aliveB && (((uB >> 12) & 15u) == 5u) && (((uB >> 8) & 15u) == 5u));
    while (b55) {
      int idx = __builtin_ctzll(b55); b55 &= b55 - 1ull;
      uint tk = (uint)__builtin_amdgcn_readlane((int)uB, idx);
      int a = tk >> 16;
      float rmv = __int_as_float(__builtin_amdgcn_readlane(__float_as_int(rm_own), a));
      float fv = (float)(tk & 255u) * rmv;
      const float2* ws2 = (const float2*)(wself + a * 256);
      float2 w0 = ws2[lane], w1 = ws2[64 + lane];
      saB.x = fmaf(fv, w0.x, saB.x);  saB.y = fmaf(fv, w0.y, saB.y);
      sbB.x = fmaf(fv, w1.x, sbB.x);  sbB.y = fmaf(fv, w1.y, sbB.y);
    }
  }

  // ---- token loop: 4 tokens/iter; 16 branch-free loads then reg-only FMAs ----
  float aA0[9] = {0,0,0,0,0,0,0,0,0}, aA1[9] = {0,0,0,0,0,0,0,0,0};
  float aB0[9] = {0,0,0,0,0,0,0,0,0}, aB1[9] = {0,0,0,0,0,0,0,0,0};
  ull mA = balA2, mB = balB2;
  int tmax;
  { int pa = __popcll(mA), pb = __popcll(mB);
    int mx = pa > pb ? pa : pb;  tmax = (mx + 1) >> 1; }
  for (int t = 0; t < tmax; ++t) {
    uint tkA0, tkA1, tkB0, tkB1;
    NEXT_TOKEN(mA, uA, tkA0)
    NEXT_TOKEN(mA, uA, tkA1)
    NEXT_TOKEN(mB, uB, tkB0)
    NEXT_TOKEN(mB, uB, tkB1)
    TB_DECODE(A0, tkA0)
    TB_DECODE(A1, tkA1)
    TB_DECODE(B0, tkB0)
    TB_DECODE(B1, tkB1)
    TB_FMA(A0, aA0, aA1)
    TB_FMA(A1, aA0, aA1)
    TB_FMA(B0, aB0, aB1)
    TB_FMA(B1, aB0, aB1)
  }

  // ---- epilogues ----
  const float2* bs2 = (const float2*)bself;
  const float2 bsp0 = bs2[lane], bsp1 = bs2[64 + lane];
  const float2 bc = ((const float2*)bc1)[lane];

  {
    float2 o0 = { fmaxf(saA.x + bsp0.x, 0.f), fmaxf(saA.y + bsp0.y, 0.f) };
    float2 o1 = { fmaxf(sbA.x + bsp1.x, 0.f), fmaxf(sbA.y + bsp1.y, 0.f) };
    float2* out2 = (float2*)(out + HID0 + bA * 512);
    out2[lane] = o0;  out2[64 + lane] = o1;
    uint wds[9];
    wds[0] = cvtpk(fmaxf(aA0[0]+bc.x,0.f), fmaxf(aA0[1]+bc.x,0.f));
    wds[1] = cvtpk(fmaxf(aA0[2]+bc.x,0.f), fmaxf(aA0[3]+bc.x,0.f));
    wds[2] = cvtpk(fmaxf(aA0[4]+bc.x,0.f), fmaxf(aA0[5]+bc.x,0.f));
    wds[3] = cvtpk(fmaxf(aA0[6]+bc.x,0.f), fmaxf(aA0[7]+bc.x,0.f));
    wds[4] = cvtpk(fmaxf(aA0[8]+bc.x,0.f), fmaxf(aA1[0]+bc.y,0.f));
    wds[5] = cvtpk(fmaxf(aA1[1]+bc.y,0.f), fmaxf(aA1[2]+bc.y,0.f));
    wds[6] = cvtpk(fmaxf(aA1[3]+bc.y,0.f), fmaxf(aA1[4]+bc.y,0.f));
    wds[7] = cvtpk(fmaxf(aA1[5]+bc.y,0.f), fmaxf(aA1[6]+bc.y,0.f));
    wds[8] = cvtpk(fmaxf(aA1[7]+bc.y,0.f), fmaxf(aA1[8]+bc.y,0.f));
    uint* dst = (uint*)h1g + bA * 576 + 9 * lane;
    #pragma unroll
    for (int j = 0; j < 9; ++j) dst[j] = wds[j];
  }
  {
    float2 o0 = { fmaxf(saB.x + bsp0.x, 0.f), fmaxf(saB.y + bsp0.y, 0.f) };
    float2 o1 = { fmaxf(sbB.x + bsp1.x, 0.f), fmaxf(sbB.y + bsp1.y, 0.f) };
    float2* out2 = (float2*)(out + HID0 + bB * 512);
    out2[lane] = o0;  out2[64 + lane] = o1;
    uint wds[9];
    wds[0] = cvtpk(fmaxf(aB0[0]+bc.x,0.f), fmaxf(aB0[1]+bc.x,0.f));
    wds[1] = cvtpk(fmaxf(aB0[2]+bc.x,0.f), fmaxf(aB0[3]+bc.x,0.f));
    wds[2] = cvtpk(fmaxf(aB0[4]+bc.x,0.f), fmaxf(aB0[5]+bc.x,0.f));
    wds[3] = cvtpk(fmaxf(aB0[6]+bc.x,0.f), fmaxf(aB0[7]+bc.x,0.f));
    wds[4] = cvtpk(fmaxf(aB0[8]+bc.x,0.f), fmaxf(aB1[0]+bc.y,0.f));
    wds[5] = cvtpk(fmaxf(aB1[1]+bc.y,0.f), fmaxf(aB1[2]+bc.y,0.f));
    wds[6] = cvtpk(fmaxf(aB1[3]+bc.y,0.f), fmaxf(aB1[4]+bc.y,0.f));
    wds[7] = cvtpk(fmaxf(aB1[5]+bc.y,0.f), fmaxf(aB1[6]+bc.y,0.f));
    wds[8] = cvtpk(fmaxf(aB1[7]+bc.y,0.f), fmaxf(aB1[8]+bc.y,0.f));
    uint* dst = (uint*)h1g + bB * 576 + 9 * lane;
    #pragma unroll
    for (int j = 0; j < 9; ++j) dst[j] = wds[j];
  }
}

// ---------------- kernel 2: conv2 + fc + heads via MFMA ----------------
extern "C" __global__ __launch_bounds__(256)
void k_mlp(const ushort* __restrict__ h1g, const ushort* __restrict__ w2f,
           const float* __restrict__ bc2, const ushort* __restrict__ wfcf,
           const float* __restrict__ bfc, const ushort* __restrict__ whf,
           const float* __restrict__ ba0, const float* __restrict__ ba1,
           const float* __restrict__ bv, float* __restrict__ out)
{
  __shared__ short  Abuf[2][4][64][8];   // 8 KB
  __shared__ ushort h2A[16][64][8];      // 16 KB

  const int tid = threadIdx.x, lane = tid & 63, w = tid >> 6;
  const int lo = lane & 15, hi = lane >> 4;
  const int bb = blockIdx.x, b0 = bb * 64;

  const short8* w2fv  = (const short8*)w2f;
  const short8* wfcfv = (const short8*)wfcf;
  const uint4*  A4    = (const uint4*)h1g;
  const long    arow  = (long)(b0 + (tid >> 2)) * 144 + (tid & 3);

  // ---- conv2: wave w owns cols (2w,2w+1)*16, all 64 rows ----
  float4_ acc[4][2];
  #pragma unroll
  for (int cgi = 0; cgi < 2; ++cgi) {
    float bv_ = bc2[(2*w + cgi)*16 + lo];
    float4_ t = {bv_, bv_, bv_, bv_};
    #pragma unroll
    for (int m = 0; m < 4; ++m) acc[m][cgi] = t;
  }

  uint4 rA = A4[arow];
  for (int t = 0; t < 36; ++t) {
    const int cur = t & 1;
    *(uint4*)&Abuf[cur][tid & 3][tid >> 2][0] = rA;
    if (t + 1 < 36) rA = A4[arow + (t + 1) * 4];
    __syncthreads();
    short8 af[4];
    #pragma unroll
    for (int m = 0; m < 4; ++m)
      af[m] = *(const short8*)&Abuf[cur][hi][m*16 + lo][0];
    #pragma unroll
    for (int cgi = 0; cgi < 2; ++cgi) {
      short8 bf = w2fv[(t*8 + 2*w + cgi)*64 + lane];
      #pragma unroll
      for (int m = 0; m < 4; ++m)
        acc[m][cgi] = __builtin_amdgcn_mfma_f32_16x16x32_bf16(af[m], bf, acc[m][cgi], 0, 0, 0);
    }
  }
  __syncthreads();

  // h2 -> LDS bf16 (A-frag layout)
  #pragma unroll
  for (int cgi = 0; cgi < 2; ++cgi) {
    int col = (2*w + cgi)*16 + lo;
    #pragma unroll
    for (int m = 0; m < 4; ++m)
      #pragma unroll
      for (int q = 0; q < 4; ++q) {
        int R = m*16 + hi*4 + q;
        h2A[col >> 3][R][col & 7] = f2bf(fmaxf(acc[m][cgi][q], 0.f));
      }
  }
  __syncthreads();

  // ---- fc: wave w owns cols (4w..4w+3)*16 ----
  float4_ acc2[4][4];
  #pragma unroll
  for (int cgi = 0; cgi < 4; ++cgi) {
    float bv_ = bfc[(4*w + cgi)*16 + lo];
    float4_ t = {bv_, bv_, bv_, bv_};
    #pragma unroll
    for (int m = 0; m < 4; ++m) acc2[m][cgi] = t;
  }
  #pragma unroll
  for (int ks = 0; ks < 4; ++ks) {
    short8 af[4];
    #pragma unroll
    for (int m = 0; m < 4; ++m)
      af[m] = *(const short8*)&h2A[ks*4 + hi][m*16 + lo][0];
    #pragma unroll
    for (int cgi = 0; cgi < 4; ++cgi) {
      short8 bf = wfcfv[(ks*16 + 4*w + cgi)*64 + lane];
      #pragma unroll
      for (int m = 0; m < 4; ++m)
        acc2[m][cgi] = __builtin_amdgcn_mfma_f32_16x16x32_bf16(af[m], bf, acc2[m][cgi], 0, 0, 0);
    }
  }

  // cnn_feat -> out hidden[:, 256:512]
  #pragma unroll
  for (int cgi = 0; cgi < 4; ++cgi) {
    int col = (4*w + cgi)*16 + lo;
    #pragma unroll
    for (int m = 0; m < 4; ++m)
      #pragma unroll
      for (int q = 0; q < 4; ++q) {
        int R = m*16 + hi*4 + q;
        out[HID0 + (long)(b0 + R)*512 + 256 + col] = fmaxf(acc2[m][cgi][q], 0.f);
      }
  }
  __syncthreads();   // drain stores; hidden rows b0..b0+63 visible block-wide

  // ---- heads: wave w owns rows w*16..w*16+15, cols 0..31 ----
  const short8* whfv = (const short8*)whf;
  float4_ acc3[2];
  #pragma unroll
  for (int cg = 0; cg < 2; ++cg) {
    int col = cg*16 + lo;
    float bias = (col < 9) ? ba0[col] : (col < 19) ? ba1[col - 9]
               : (col == 19) ? bv[0] : 0.f;
    float4_ t = {bias, bias, bias, bias};
    acc3[cg] = t;
  }

  const float* hrow = out + HID0 + (long)(b0 + w*16 + lo) * 512;
  #pragma unroll
  for (int ks = 0; ks < 16; ++ks) {
    float4_ f0 = *(const float4_*)(hrow + ks*32 + hi*8);
    float4_ f1 = *(const float4_*)(hrow + ks*32 + hi*8 + 4);
    union { short8 s; ushort u[8]; } afu;
    afu.u[0] = f2bf(f0[0]); afu.u[1] = f2bf(f0[1]);
    afu.u[2] = f2bf(f0[2]); afu.u[3] = f2bf(f0[3]);
    afu.u[4] = f2bf(f1[0]); afu.u[5] = f2bf(f1[1]);
    afu.u[6] = f2bf(f1[2]); afu.u[7] = f2bf(f1[3]);
    #pragma unroll
    for (int cg = 0; cg < 2; ++cg) {
      short8 bf = whfv[(ks*2 + cg)*64 + lane];
      acc3[cg] = __builtin_amdgcn_mfma_f32_16x16x32_bf16(afu.s, bf, acc3[cg], 0, 0, 0);
    }
  }

  #pragma unroll
  for (int cg = 0; cg < 2; ++cg) {
    int col = cg*16 + lo;
    #pragma unroll
    for (int q = 0; q < 4; ++q) {
      long R = b0 + w*16 + hi*4 + q;
      float v = acc3[cg][q];
      if (col < 9)        out[R*9 + col] = v;
      else if (col < 19)  out[(long)B_TOT*9 + R*10 + (col - 9)] = v;
      else if (col == 19) out[(long)B_TOT*19 + R] = v;
    }
  }
}

extern "C" void kernel_launch(void* const* d_in, const int* in_sizes, int n_in,
                              void* d_out, int out_size, void* d_ws, size_t ws_size,
                              hipStream_t stream) {
  const int* obs      = (const int*)d_in[0];
  const float* maxvec = (const float*)d_in[1];
  const float* wc1    = (const float*)d_in[2];
  const float* bc1    = (const float*)d_in[3];
  const float* wc2    = (const float*)d_in[4];
  const float* bc2    = (const float*)d_in[5];
  const float* wfc    = (const float*)d_in[6];
  const float* bfc    = (const float*)d_in[7];
  const float* wself  = (const float*)d_in[8];
  const float* bself  = (const float*)d_in[9];
  const float* wa0    = (const float*)d_in[10];
  const float* ba0    = (const float*)d_in[11];
  const float* wa1    = (const float*)d_in[12];
  const float* ba1    = (const float*)d_in[13];
  const float* wv     = (const float*)d_in[14];
  const float* bv     = (const float*)d_in[15];
  float* out          = (float*)d_out;

  char* ws = (char*)d_ws;
  ushort* w2f  = (ushort*)(ws + W2F_OFF);
  ushort* wfcf = (ushort*)(ws + WFCF_OFF);
  ushort* whf  = (ushort*)(ws + WHF_OFF);
  uint*   w1p  = (uint*)(ws + W1P_OFF);
  ushort* h1g  = (ushort*)(ws + H1_OFF);

  k_prep  <<<dim3(234),      dim3(256), 0, stream>>>(wc1, wc2, wfc, wa0, wa1, wv,
                                                     w2f, wfcf, whf, w1p);
  k_encode<<<dim3(B_TOT/8),  dim3(256), 0, stream>>>(obs, maxvec, w1p, bc1,
                                                     wself, bself, out, h1g);
  k_mlp   <<<dim3(B_TOT/64), dim3(256), 0, stream>>>(h1g, w2f, bc2, wfcf, bfc,
                                                     whf, ba0, ba1, bv, out);
}

// Round 17
// 99.291 us; speedup vs baseline: 1.3279x; 1.3279x over previous
//
#include <hip/hip_runtime.h>
#include <hip/hip_bf16.h>

typedef unsigned int uint;
typedef unsigned short ushort;
typedef unsigned long long ull;
typedef __attribute__((ext_vector_type(8))) short short8;
typedef __attribute__((ext_vector_type(4))) float float4_;

#define B_TOT 32768
#define NL    22
#define HID0  ((long)B_TOT * 20)

// ws layout (bytes), 16B aligned
#define W2F_OFF  0          // conv2 B-frags bf16 (k = ic*9+p): 294,912
#define WFCF_OFF 294912     // fc    B-frags bf16: 65,536
#define WHF_OFF  360448     // heads B-frags bf16: 32,768
#define W1P_OFF  393216     // conv1 W^T bf16-pairs: 551*64*4 = 141,056
#define H1_OFF   534272     // h1 row-major bf16: 32768*1152*2 = 75,497,472
// total 76,031,744

__device__ __forceinline__ ushort f2bf(float v) {
  uint x = __float_as_uint(v);
  x += 0x7fffu + ((x >> 16) & 1u);
  return (ushort)(x >> 16);
}
__device__ __forceinline__ uint cvtpk(float lo, float hi) {
  uint r;
  asm volatile("v_cvt_pk_bf16_f32 %0, %1, %2" : "=v"(r) : "v"(lo), "v"(hi));
  return r;
}
struct u3 { uint x, y, z; };

// ---------------- prologue: weight repack ----------------
extern "C" __global__ __launch_bounds__(256)
void k_prep(const float* __restrict__ wc1, const float* __restrict__ wc2,
            const float* __restrict__ wfc,
            const float* __restrict__ wa0, const float* __restrict__ wa1,
            const float* __restrict__ wv,
            ushort* __restrict__ w2f, ushort* __restrict__ wfcf,
            ushort* __restrict__ whf, uint* __restrict__ w1p)
{
  int i = blockIdx.x * 256 + threadIdx.x;
  if (i < 18432) {            // conv2 B-frags: B[k][col] = wc2[col][k], k = ic*9+p
    int l = i & 63, cg = (i >> 6) & 7, ks = i >> 9;
    int col = cg * 16 + (l & 15), kb = ks * 32 + (l >> 4) * 8;
    ushort t[8];
    #pragma unroll
    for (int j = 0; j < 8; ++j) t[j] = f2bf(wc2[col * 1152 + kb + j]);
    uint4 o = { (uint)t[0]|((uint)t[1]<<16), (uint)t[2]|((uint)t[3]<<16),
                (uint)t[4]|((uint)t[5]<<16), (uint)t[6]|((uint)t[7]<<16) };
    ((uint4*)w2f)[i] = o;
  } else if (i < 22528) {     // fc: B[k][col] = wfc[k][col]
    int i2 = i - 18432;
    int l = i2 & 63, cg = (i2 >> 6) & 15, ks = i2 >> 10;
    int col = cg * 16 + (l & 15), kb = ks * 32 + (l >> 4) * 8;
    ushort t[8];
    #pragma unroll
    for (int j = 0; j < 8; ++j) t[j] = f2bf(wfc[(kb + j) * 256 + col]);
    uint4 o = { (uint)t[0]|((uint)t[1]<<16), (uint)t[2]|((uint)t[3]<<16),
                (uint)t[4]|((uint)t[5]<<16), (uint)t[6]|((uint)t[7]<<16) };
    ((uint4*)wfcf)[i2] = o;
  } else if (i < 24576) {     // heads: cols 0..8 wa0, 9..18 wa1, 19 wv, 20..31 zero
    int i2 = i - 22528;
    int l = i2 & 63, cg = (i2 >> 6) & 1, ks = i2 >> 7;
    int col = cg * 16 + (l & 15), kb = ks * 32 + (l >> 4) * 8;
    ushort t[8];
    #pragma unroll
    for (int j = 0; j < 8; ++j) {
      int k = kb + j;
      float v = (col < 9)  ? wa0[k*9 + col]
              : (col < 19) ? wa1[k*10 + (col - 9)]
              : (col == 19) ? wv[k] : 0.f;
      t[j] = f2bf(v);
    }
    uint4 o = { (uint)t[0]|((uint)t[1]<<16), (uint)t[2]|((uint)t[3]<<16),
                (uint)t[4]|((uint)t[5]<<16), (uint)t[6]|((uint)t[7]<<16) };
    ((uint4*)whf)[i2] = o;
  } else if (i < 24576 + 35264) {   // w1p: 550 packed rows (+spare row)
    int j = i - 24576;
    int l = j & 63, r = j >> 6;
    uint val = 0u;
    if (r < 550) {
      ushort lo_ = f2bf(wc1[(2*l)     * 550 + r]);
      ushort hi_ = f2bf(wc1[(2*l + 1) * 550 + r]);
      val = (uint)lo_ | ((uint)hi_ << 16);
    }
    w1p[j] = val;
  }
}

// conv positions of one scalar token -> named accumulators (scalar branches)
#define PROC_CONV(tk, acc0, acc1)                                          \
  {                                                                        \
    const int a = (int)((tk) >> 16), x = (int)(((tk) >> 12) & 15u),        \
              y = (int)(((tk) >> 8) & 15u);                                \
    const float rmv = __int_as_float(                                      \
        __builtin_amdgcn_readlane(__float_as_int(rm_own), a));             \
    const float fv = (float)((tk) & 255u) * rmv;                           \
    const int wbase = a * 25;                                              \
    _Pragma("unroll")                                                      \
    for (int ox = 0; ox < 3; ++ox) {                                       \
      int kx = x - 3 * ox;                                                 \
      if ((unsigned)kx > 4u) continue;            /* s_cmp + s_cbranch */  \
      _Pragma("unroll")                                                    \
      for (int oy = 0; oy < 3; ++oy) {                                     \
        int ky = y - 3 * oy;                                               \
        if ((unsigned)ky > 4u) continue;                                   \
        uint wu = w1p[(wbase + kx * 5 + ky) * 64 + lane];                  \
        acc0[ox*3+oy] = fmaf(fv, __uint_as_float(wu << 16),                \
                             acc0[ox*3+oy]);                               \
        acc1[ox*3+oy] = fmaf(fv, __uint_as_float(wu & 0xffff0000u),        \
                             acc1[ox*3+oy]);                               \
      }                                                                    \
    }                                                                      \
  }

// ---------------- kernel 1: tokens -> sparse conv1 + self head ----------------
// 2 samples/wave; ballot-mask token iteration (registers only in hot loop).
// This is the round-13 structure — best measured of 7 encode variants.
extern "C" __global__ __launch_bounds__(256)
void k_encode(const int* __restrict__ obs, const float* __restrict__ maxvec,
              const uint* __restrict__ w1p, const float* __restrict__ bc1,
              const float* __restrict__ wself, const float* __restrict__ bself,
              float* __restrict__ out, ushort* __restrict__ h1g)
{
  __shared__ uint klist[8][64];

  const int tid = threadIdx.x, lane = tid & 63, w = tid >> 6;
  const long bA = (long)blockIdx.x * 8 + w * 2;
  const long bB = bA + 1;

  float rm_own = (lane < NL) ? (1.0f / maxvec[lane]) : 0.f;

  const uint* obA = (const uint*)obs + bA * 600;
  const uint* obB = (const uint*)obs + bB * 600;
  uint* klA = klist[w * 2 + 0];
  uint* klB = klist[w * 2 + 1];

  // ---- decode + ordered compaction, A/B interleaved ----
  int cntA = 0, cntB = 0;
  #pragma unroll
  for (int r = 0; r < 4; ++r) {
    int m = r * 64 + lane;
    bool vA = false, vB = false; uint pkA = 0, pkB = 0;
    if (m < 200) {
      u3 tA = *(const u3*)(obA + m * 3);
      u3 tB = *(const u3*)(obB + m * 3);
      uint cA = tA.x, aA = tA.y, vvA = tA.z;
      uint cB = tB.x, aB = tB.y, vvB = tB.z;
      cA = (cA == 255u) ? 0u : cA;  aA = (aA == 255u) ? 0u : aA;  vvA = (vvA == 255u) ? 0u : vvA;
      cB = (cB == 255u) ? 0u : cB;  aB = (aB == 255u) ? 0u : aB;  vvB = (vvB == 255u) ? 0u : vvB;
      uint xA = (cA >> 4) & 15u, yA = cA & 15u;
      uint xB = (cB >> 4) & 15u, yB = cB & 15u;
      vA = (xA < 11u) && (yA < 11u) && (aA < NL);
      vB = (xB < 11u) && (yB < 11u) && (aB < NL);
      pkA = (aA << 16) | (xA << 12) | (yA << 8) | vvA;
      pkB = (aB << 16) | (xB << 12) | (yB << 8) | vvB;
    }
    ull balA = __ballot(vA);
    if (vA) {
      int pos = cntA + __popcll(balA & ((1ull << lane) - 1ull));
      if (pos < 64) klA[pos] = pkA;
    }
    cntA += __popcll(balA);
    ull balB = __ballot(vB);
    if (vB) {
      int pos = cntB + __popcll(balB & ((1ull << lane) - 1ull));
      if (pos < 64) klB[pos] = pkB;
    }
    cntB += __popcll(balB);
  }
  if (cntA > 64) cntA = 64;
  if (cntB > 64) cntB = 64;

  // ---- dedup (last write wins) in registers, fused shfl ring scan ----
  uint uA = (lane < cntA) ? klA[lane] : 0xffffffffu;
  uint uB = (lane < cntB) ? klB[lane] : 0xffffffffu;
  uint cellA = uA >> 8, cellB = uB >> 8;
  bool aliveA = (lane < cntA), aliveB = (lane < cntB);
  const int dmax = (cntA > cntB) ? cntA : cntB;
  for (int d = 1; d < dmax; ++d) {
    uint oA = __shfl_down(cellA, d);
    uint oB = __shfl_down(cellB, d);
    aliveA = aliveA && !((lane + d < cntA) && (oA == cellA));
    aliveB = aliveB && !((lane + d < cntB) && (oB == cellB));
  }
  const ull balA2 = __ballot(aliveA);
  const ull balB2 = __ballot(aliveB);

  // ---- self head: rare (5,5) tokens, uniform scalar pre-pass ----
  float2 saA = {0.f,0.f}, sbA = {0.f,0.f}, saB = {0.f,0.f}, sbB = {0.f,0.f};
  {
    ull b55 = __ballot(aliveA && (((uA >> 12) & 15u) == 5u) && (((uA >> 8) & 15u) == 5u));
    while (b55) {
      int idx = __builtin_ctzll(b55); b55 &= b55 - 1ull;
      uint tk = (uint)__builtin_amdgcn_readlane((int)uA, idx);
      int a = tk >> 16;
      float rmv = __int_as_float(__builtin_amdgcn_readlane(__float_as_int(rm_own), a));
      float fv = (float)(tk & 255u) * rmv;
      const float2* ws2 = (const float2*)(wself + a * 256);
      float2 w0 = ws2[lane], w1 = ws2[64 + lane];
      saA.x = fmaf(fv, w0.x, saA.x);  saA.y = fmaf(fv, w0.y, saA.y);
      sbA.x = fmaf(fv, w1.x, sbA.x);  sbA.y = fmaf(fv, w1.y, sbA.y);
    }
    b55 = __ballot(aliveB && (((uB >> 12) & 15u) == 5u) && (((uB >> 8) & 15u) == 5u));
    while (b55) {
      int idx = __builtin_ctzll(b55); b55 &= b55 - 1ull;
      uint tk = (uint)__builtin_amdgcn_readlane((int)uB, idx);
      int a = tk >> 16;
      float rmv = __int_as_float(__builtin_amdgcn_readlane(__float_as_int(rm_own), a));
      float fv = (float)(tk & 255u) * rmv;
      const float2* ws2 = (const float2*)(wself + a * 256);
      float2 w0 = ws2[lane], w1 = ws2[64 + lane];
      saB.x = fmaf(fv, w0.x, saB.x);  saB.y = fmaf(fv, w0.y, saB.y);
      sbB.x = fmaf(fv, w1.x, sbB.x);  sbB.y = fmaf(fv, w1.y, sbB.y);
    }
  }

  // ---- token loop: iterate ballot masks, token fetch = v_readlane ----
  float aA0[9] = {0,0,0,0,0,0,0,0,0}, aA1[9] = {0,0,0,0,0,0,0,0,0};
  float aB0[9] = {0,0,0,0,0,0,0,0,0}, aB1[9] = {0,0,0,0,0,0,0,0,0};
  ull mA = balA2, mB = balB2;
  while (mA | mB) {
    if (mA) {
      int idx = __builtin_ctzll(mA); mA &= mA - 1ull;
      const uint tk = (uint)__builtin_amdgcn_readlane((int)uA, idx);
      PROC_CONV(tk, aA0, aA1);
    }
    if (mB) {
      int idx = __builtin_ctzll(mB); mB &= mB - 1ull;
      const uint tk = (uint)__builtin_amdgcn_readlane((int)uB, idx);
      PROC_CONV(tk, aB0, aB1);
    }
  }

  // ---- epilogues ----
  const float2* bs2 = (const float2*)bself;
  const float2 bsp0 = bs2[lane], bsp1 = bs2[64 + lane];
  const float2 bc = ((const float2*)bc1)[lane];

  {
    float2 o0 = { fmaxf(saA.x + bsp0.x, 0.f), fmaxf(saA.y + bsp0.y, 0.f) };
    float2 o1 = { fmaxf(sbA.x + bsp1.x, 0.f), fmaxf(sbA.y + bsp1.y, 0.f) };
    float2* out2 = (float2*)(out + HID0 + bA * 512);
    out2[lane] = o0;  out2[64 + lane] = o1;
    uint wds[9];
    wds[0] = cvtpk(fmaxf(aA0[0]+bc.x,0.f), fmaxf(aA0[1]+bc.x,0.f));
    wds[1] = cvtpk(fmaxf(aA0[2]+bc.x,0.f), fmaxf(aA0[3]+bc.x,0.f));
    wds[2] = cvtpk(fmaxf(aA0[4]+bc.x,0.f), fmaxf(aA0[5]+bc.x,0.f));
    wds[3] = cvtpk(fmaxf(aA0[6]+bc.x,0.f), fmaxf(aA0[7]+bc.x,0.f));
    wds[4] = cvtpk(fmaxf(aA0[8]+bc.x,0.f), fmaxf(aA1[0]+bc.y,0.f));
    wds[5] = cvtpk(fmaxf(aA1[1]+bc.y,0.f), fmaxf(aA1[2]+bc.y,0.f));
    wds[6] = cvtpk(fmaxf(aA1[3]+bc.y,0.f), fmaxf(aA1[4]+bc.y,0.f));
    wds[7] = cvtpk(fmaxf(aA1[5]+bc.y,0.f), fmaxf(aA1[6]+bc.y,0.f));
    wds[8] = cvtpk(fmaxf(aA1[7]+bc.y,0.f), fmaxf(aA1[8]+bc.y,0.f));
    uint* dst = (uint*)h1g + bA * 576 + 9 * lane;
    #pragma unroll
    for (int j = 0; j < 9; ++j) dst[j] = wds[j];
  }
  {
    float2 o0 = { fmaxf(saB.x + bsp0.x, 0.f), fmaxf(saB.y + bsp0.y, 0.f) };
    float2 o1 = { fmaxf(sbB.x + bsp1.x, 0.f), fmaxf(sbB.y + bsp1.y, 0.f) };
    float2* out2 = (float2*)(out + HID0 + bB * 512);
    out2[lane] = o0;  out2[64 + lane] = o1;
    uint wds[9];
    wds[0] = cvtpk(fmaxf(aB0[0]+bc.x,0.f), fmaxf(aB0[1]+bc.x,0.f));
    wds[1] = cvtpk(fmaxf(aB0[2]+bc.x,0.f), fmaxf(aB0[3]+bc.x,0.f));
    wds[2] = cvtpk(fmaxf(aB0[4]+bc.x,0.f), fmaxf(aB0[5]+bc.x,0.f));
    wds[3] = cvtpk(fmaxf(aB0[6]+bc.x,0.f), fmaxf(aB0[7]+bc.x,0.f));
    wds[4] = cvtpk(fmaxf(aB0[8]+bc.x,0.f), fmaxf(aB1[0]+bc.y,0.f));
    wds[5] = cvtpk(fmaxf(aB1[1]+bc.y,0.f), fmaxf(aB1[2]+bc.y,0.f));
    wds[6] = cvtpk(fmaxf(aB1[3]+bc.y,0.f), fmaxf(aB1[4]+bc.y,0.f));
    wds[7] = cvtpk(fmaxf(aB1[5]+bc.y,0.f), fmaxf(aB1[6]+bc.y,0.f));
    wds[8] = cvtpk(fmaxf(aB1[7]+bc.y,0.f), fmaxf(aB1[8]+bc.y,0.f));
    uint* dst = (uint*)h1g + bB * 576 + 9 * lane;
    #pragma unroll
    for (int j = 0; j < 9; ++j) dst[j] = wds[j];
  }
}

// ---------------- kernel 2: conv2 + fc + heads via MFMA ----------------
// NEW: fc result (cnn half of hidden) is kept in LDS bf16 (hcnn) so the
// heads phase reads only the self half from global (-33.5 MB traffic).
extern "C" __global__ __launch_bounds__(256)
void k_mlp(const ushort* __restrict__ h1g, const ushort* __restrict__ w2f,
           const float* __restrict__ bc2, const ushort* __restrict__ wfcf,
           const float* __restrict__ bfc, const ushort* __restrict__ whf,
           const float* __restrict__ ba0, const float* __restrict__ ba1,
           const float* __restrict__ bv, float* __restrict__ out)
{
  __shared__ short  Abuf[2][4][64][8];   //  8 KB
  __shared__ ushort h2A[16][64][8];      // 16 KB
  __shared__ ushort hcnn[32][64][8];     // 32 KB (cnn half, A-frag layout)

  const int tid = threadIdx.x, lane = tid & 63, w = tid >> 6;
  const int lo = lane & 15, hi = lane >> 4;
  const int bb = blockIdx.x, b0 = bb * 64;

  const short8* w2fv  = (const short8*)w2f;
  const short8* wfcfv = (const short8*)wfcf;
  const uint4*  A4    = (const uint4*)h1g;
  const long    arow  = (long)(b0 + (tid >> 2)) * 144 + (tid & 3);

  // ---- conv2: wave w owns cols (2w,2w+1)*16, all 64 rows ----
  float4_ acc[4][2];
  #pragma unroll
  for (int cgi = 0; cgi < 2; ++cgi) {
    float bv_ = bc2[(2*w + cgi)*16 + lo];
    float4_ t = {bv_, bv_, bv_, bv_};
    #pragma unroll
    for (int m = 0; m < 4; ++m) acc[m][cgi] = t;
  }

  uint4 rA = A4[arow];
  for (int t = 0; t < 36; ++t) {
    const int cur = t & 1;
    *(uint4*)&Abuf[cur][tid & 3][tid >> 2][0] = rA;
    if (t + 1 < 36) rA = A4[arow + (t + 1) * 4];
    __syncthreads();
    short8 af[4];
    #pragma unroll
    for (int m = 0; m < 4; ++m)
      af[m] = *(const short8*)&Abuf[cur][hi][m*16 + lo][0];
    #pragma unroll
    for (int cgi = 0; cgi < 2; ++cgi) {
      short8 bf = w2fv[(t*8 + 2*w + cgi)*64 + lane];
      #pragma unroll
      for (int m = 0; m < 4; ++m)
        acc[m][cgi] = __builtin_amdgcn_mfma_f32_16x16x32_bf16(af[m], bf, acc[m][cgi], 0, 0, 0);
    }
  }
  __syncthreads();

  // h2 -> LDS bf16 (A-frag layout)
  #pragma unroll
  for (int cgi = 0; cgi < 2; ++cgi) {
    int col = (2*w + cgi)*16 + lo;
    #pragma unroll
    for (int m = 0; m < 4; ++m)
      #pragma unroll
      for (int q = 0; q < 4; ++q) {
        int R = m*16 + hi*4 + q;
        h2A[col >> 3][R][col & 7] = f2bf(fmaxf(acc[m][cgi][q], 0.f));
      }
  }
  __syncthreads();

  // ---- fc: wave w owns cols (4w..4w+3)*16 ----
  float4_ acc2[4][4];
  #pragma unroll
  for (int cgi = 0; cgi < 4; ++cgi) {
    float bv_ = bfc[(4*w + cgi)*16 + lo];
    float4_ t = {bv_, bv_, bv_, bv_};
    #pragma unroll
    for (int m = 0; m < 4; ++m) acc2[m][cgi] = t;
  }
  #pragma unroll
  for (int ks = 0; ks < 4; ++ks) {
    short8 af[4];
    #pragma unroll
    for (int m = 0; m < 4; ++m)
      af[m] = *(const short8*)&h2A[ks*4 + hi][m*16 + lo][0];
    #pragma unroll
    for (int cgi = 0; cgi < 4; ++cgi) {
      short8 bf = wfcfv[(ks*16 + 4*w + cgi)*64 + lane];
      #pragma unroll
      for (int m = 0; m < 4; ++m)
        acc2[m][cgi] = __builtin_amdgcn_mfma_f32_16x16x32_bf16(af[m], bf, acc2[m][cgi], 0, 0, 0);
    }
  }

  // cnn_feat -> out hidden[:, 256:512] (fp32) AND hcnn (bf16, A-frag layout)
  #pragma unroll
  for (int cgi = 0; cgi < 4; ++cgi) {
    int col = (4*w + cgi)*16 + lo;
    #pragma unroll
    for (int m = 0; m < 4; ++m)
      #pragma unroll
      for (int q = 0; q < 4; ++q) {
        int R = m*16 + hi*4 + q;
        float v = fmaxf(acc2[m][cgi][q], 0.f);
        out[HID0 + (long)(b0 + R)*512 + 256 + col] = v;
        hcnn[col >> 3][R][col & 7] = f2bf(v);
      }
  }
  __syncthreads();   // hcnn + self-half (from k_encode, global) ready

  // ---- heads: wave w owns rows w*16..w*16+15, cols 0..31 ----
  // self half (k 0..255) from global; cnn half (k 256..511) from hcnn LDS.
  const short8* whfv = (const short8*)whf;
  float4_ acc3[2];
  #pragma unroll
  for (int cg = 0; cg < 2; ++cg) {
    int col = cg*16 + lo;
    float bias = (col < 9) ? ba0[col] : (col < 19) ? ba1[col - 9]
               : (col == 19) ? bv[0] : 0.f;
    float4_ t = {bias, bias, bias, bias};
    acc3[cg] = t;
  }

  const float* hrow = out + HID0 + (long)(b0 + w*16 + lo) * 512;
  #pragma unroll
  for (int ks = 0; ks < 8; ++ks) {      // self half: global fp32 -> bf16
    float4_ f0 = *(const float4_*)(hrow + ks*32 + hi*8);
    float4_ f1 = *(const float4_*)(hrow + ks*32 + hi*8 + 4);
    union { short8 s; ushort u[8]; } afu;
    afu.u[0] = f2bf(f0[0]); afu.u[1] = f2bf(f0[1]);
    afu.u[2] = f2bf(f0[2]); afu.u[3] = f2bf(f0[3]);
    afu.u[4] = f2bf(f1[0]); afu.u[5] = f2bf(f1[1]);
    afu.u[6] = f2bf(f1[2]); afu.u[7] = f2bf(f1[3]);
    #pragma unroll
    for (int cg = 0; cg < 2; ++cg) {
      short8 bf = whfv[(ks*2 + cg)*64 + lane];
      acc3[cg] = __builtin_amdgcn_mfma_f32_16x16x32_bf16(afu.s, bf, acc3[cg], 0, 0, 0);
    }
  }
  #pragma unroll
  for (int ks = 8; ks < 16; ++ks) {     // cnn half: straight from LDS
    short8 af = *(const short8*)&hcnn[(ks - 8)*4 + hi][w*16 + lo][0];
    #pragma unroll
    for (int cg = 0; cg < 2; ++cg) {
      short8 bf = whfv[(ks*2 + cg)*64 + lane];
      acc3[cg] = __builtin_amdgcn_mfma_f32_16x16x32_bf16(af, bf, acc3[cg], 0, 0, 0);
    }
  }

  #pragma unroll
  for (int cg = 0; cg < 2; ++cg) {
    int col = cg*16 + lo;
    #pragma unroll
    for (int q = 0; q < 4; ++q) {
      long R = b0 + w*16 + hi*4 + q;
      float v = acc3[cg][q];
      if (col < 9)        out[R*9 + col] = v;
      else if (col < 19)  out[(long)B_TOT*9 + R*10 + (col - 9)] = v;
      else if (col == 19) out[(long)B_TOT*19 + R] = v;
    }
  }
}

extern "C" void kernel_launch(void* const* d_in, const int* in_sizes, int n_in,
                              void* d_out, int out_size, void* d_ws, size_t ws_size,
                              hipStream_t stream) {
  const int* obs      = (const int*)d_in[0];
  const float* maxvec = (const float*)d_in[1];
  const float* wc1    = (const float*)d_in[2];
  const float* bc1    = (const float*)d_in[3];
  const float* wc2    = (const float*)d_in[4];
  const float* bc2    = (const float*)d_in[5];
  const float* wfc    = (const float*)d_in[6];
  const float* bfc    = (const float*)d_in[7];
  const float* wself  = (const float*)d_in[8];
  const float* bself  = (const float*)d_in[9];
  const float* wa0    = (const float*)d_in[10];
  const float* ba0    = (const float*)d_in[11];
  const float* wa1    = (const float*)d_in[12];
  const float* ba1    = (const float*)d_in[13];
  const float* wv     = (const float*)d_in[14];
  const float* bv     = (const float*)d_in[15];
  float* out          = (float*)d_out;

  char* ws = (char*)d_ws;
  ushort* w2f  = (ushort*)(ws + W2F_OFF);
  ushort* wfcf = (ushort*)(ws + WFCF_OFF);
  ushort* whf  = (ushort*)(ws + WHF_OFF);
  uint*   w1p  = (uint*)(ws + W1P_OFF);
  ushort* h1g  = (ushort*)(ws + H1_OFF);

  k_prep  <<<dim3(234),      dim3(256), 0, stream>>>(wc1, wc2, wfc, wa0, wa1, wv,
                                                     w2f, wfcf, whf, w1p);
  k_encode<<<dim3(B_TOT/8),  dim3(256), 0, stream>>>(obs, maxvec, w1p, bc1,
                                                     wself, bself, out, h1g);
  k_mlp   <<<dim3(B_TOT/64), dim3(256), 0, stream>>>(h1g, w2f, bc2, wfcf, bfc,
                                                     whf, ba0, ba1, bv, out);
}